// Round 3
// baseline (361.174 us; speedup 1.0000x reference)
//
#include <hip/hip_runtime.h>
#include <cstdint>

typedef unsigned short u16;
typedef unsigned int   u32;
typedef _Float16 f16;

typedef __attribute__((ext_vector_type(8))) short    bf16x8;  // 8 bf16 = 4 VGPRs
typedef __attribute__((ext_vector_type(8))) _Float16 f16x8;   // 8 fp16 = 4 VGPRs
typedef __attribute__((ext_vector_type(4))) float    f32x4;   // MFMA accumulator

__device__ __forceinline__ float bf2f(u16 h) {
    union { u32 u; float f; } c; c.u = ((u32)h) << 16; return c.f;
}
__device__ __forceinline__ u16 f2bf(float f) {
    union { float f; u32 u; } c; c.f = f;
    u32 u = c.u;
    return (u16)((u + 0x7FFFu + ((u >> 16) & 1u)) >> 16);   // RTNE
}
__device__ __forceinline__ u16 f2h(float f) {
    union { f16 h; u16 u; } c; c.h = (f16)f; return c.u;    // v_cvt_f16_f32 RTNE
}

// async global->LDS, 16B per lane; LDS dest = wave-uniform base + lane*16
__device__ __forceinline__ void async_copy16(const u16* g, u16* lds) {
    __builtin_amdgcn_global_load_lds(
        (const __attribute__((address_space(1))) void*)g,
        (__attribute__((address_space(3))) void*)lds,
        16, 0, 0);
}

// ---------------------------------------------------------------------------
// Shared geometry for all NT cores: C[128,128] tile, 256 thr = 4 waves (2x2),
// each wave 64x64 as 4x4 MFMA 16x16x32.  BK=32.  LDS tile = [128][32] u16.
// ---------------------------------------------------------------------------
struct CoreIdx {
    int ra0, ra1, skc;      // staging rows + k offset
    int lbase0, lbase1;     // LDS staging bases (u16 elems)
    int fa_off;             // fragment base offset within a [128][32] tile
};
__device__ __forceinline__ CoreIdx core_idx() {
    const int t = threadIdx.x, w = t >> 6, lane = t & 63;
    CoreIdx ci;
    const int srow = lane >> 2;
    ci.skc  = (lane & 3) * 8;
    ci.ra0  = (w * 2 + 0) * 16 + srow;
    ci.ra1  = (w * 2 + 1) * 16 + srow;
    ci.lbase0 = (w * 2 + 0) * 512;
    ci.lbase1 = (w * 2 + 1) * 512;
    const int fr = lane & 15, fq = lane >> 4;
    const int wm = (w >> 1) * 64, wn = (w & 1) * 64;
    ci.fa_off = (wm + fr) * 32 + fq * 8;     // A-frag; B-frag uses wn instead
    (void)wn;
    return ci;
}

// ---- single-dtype bf16 NT core (smem: 8192 u16 = 16 KB) -------------------
__device__ __forceinline__ void gemm_nt_bf16(
    u16* smem, const u16* __restrict__ A, int lda,
    const u16* __restrict__ B, int ldb, int K, f32x4 acc[4][4])
{
    u16* As = smem; u16* Bs = smem + 4096;
    const int t = threadIdx.x, w = t >> 6, lane = t & 63;
    const int srow = lane >> 2, skc = (lane & 3) * 8;
    const int ra0 = (w*2+0)*16 + srow, ra1 = (w*2+1)*16 + srow;
    const u16* gA0 = A + (size_t)ra0 * lda + skc;
    const u16* gA1 = A + (size_t)ra1 * lda + skc;
    const u16* gB0 = B + (size_t)ra0 * ldb + skc;
    const u16* gB1 = B + (size_t)ra1 * ldb + skc;
    u16* lA0 = As + (w*2+0)*512; u16* lA1 = As + (w*2+1)*512;
    u16* lB0 = Bs + (w*2+0)*512; u16* lB1 = Bs + (w*2+1)*512;
    const int fr = lane & 15, fq = lane >> 4;
    const int wm = (w >> 1) * 64, wn = (w & 1) * 64;
    const u16* fA = As + (wm + fr) * 32 + fq * 8;
    const u16* fB = Bs + (wn + fr) * 32 + fq * 8;

    for (int k0 = 0; k0 < K; k0 += 32) {
        async_copy16(gA0 + k0, lA0);
        async_copy16(gA1 + k0, lA1);
        async_copy16(gB0 + k0, lB0);
        async_copy16(gB1 + k0, lB1);
        __syncthreads();
        bf16x8 af[4], bf[4];
#pragma unroll
        for (int i = 0; i < 4; i++) af[i] = *(const bf16x8*)(fA + i * 512);
#pragma unroll
        for (int i = 0; i < 4; i++) bf[i] = *(const bf16x8*)(fB + i * 512);
#pragma unroll
        for (int mi = 0; mi < 4; mi++)
#pragma unroll
            for (int ni = 0; ni < 4; ni++)
                acc[mi][ni] = __builtin_amdgcn_mfma_f32_16x16x32_bf16(
                    af[mi], bf[ni], acc[mi][ni], 0, 0, 0);
        __syncthreads();
    }
}

// ---- single-dtype fp16 NT core (smem: 8192 u16 = 16 KB) -------------------
__device__ __forceinline__ void gemm_nt_f16(
    u16* smem, const u16* __restrict__ A, int lda,
    const u16* __restrict__ B, int ldb, int K, f32x4 acc[4][4])
{
    u16* As = smem; u16* Bs = smem + 4096;
    const int t = threadIdx.x, w = t >> 6, lane = t & 63;
    const int srow = lane >> 2, skc = (lane & 3) * 8;
    const int ra0 = (w*2+0)*16 + srow, ra1 = (w*2+1)*16 + srow;
    const u16* gA0 = A + (size_t)ra0 * lda + skc;
    const u16* gA1 = A + (size_t)ra1 * lda + skc;
    const u16* gB0 = B + (size_t)ra0 * ldb + skc;
    const u16* gB1 = B + (size_t)ra1 * ldb + skc;
    u16* lA0 = As + (w*2+0)*512; u16* lA1 = As + (w*2+1)*512;
    u16* lB0 = Bs + (w*2+0)*512; u16* lB1 = Bs + (w*2+1)*512;
    const int fr = lane & 15, fq = lane >> 4;
    const int wm = (w >> 1) * 64, wn = (w & 1) * 64;
    const u16* fA = As + (wm + fr) * 32 + fq * 8;
    const u16* fB = Bs + (wn + fr) * 32 + fq * 8;

    for (int k0 = 0; k0 < K; k0 += 32) {
        async_copy16(gA0 + k0, lA0);
        async_copy16(gA1 + k0, lA1);
        async_copy16(gB0 + k0, lB0);
        async_copy16(gB1 + k0, lB1);
        __syncthreads();
        f16x8 af[4], bf[4];
#pragma unroll
        for (int i = 0; i < 4; i++) af[i] = *(const f16x8*)(fA + i * 512);
#pragma unroll
        for (int i = 0; i < 4; i++) bf[i] = *(const f16x8*)(fB + i * 512);
#pragma unroll
        for (int mi = 0; mi < 4; mi++)
#pragma unroll
            for (int ni = 0; ni < 4; ni++)
                acc[mi][ni] = __builtin_amdgcn_mfma_f32_16x16x32_f16(
                    af[mi], bf[ni], acc[mi][ni], 0, 0, 0);
        __syncthreads();
    }
}

// ---- split-bf16 NT core: acc += (Ah+Al)*(Bh+Bl)^T minus lo*lo term --------
// (smem: 16384 u16 = 32 KB; rel error ~2^-17 vs fp32)
__device__ __forceinline__ void gemm_nt_split(
    u16* smem,
    const u16* __restrict__ Ah, const u16* __restrict__ Al, int lda,
    const u16* __restrict__ Bh, const u16* __restrict__ Bl, int ldb,
    int K, f32x4 acc[4][4])
{
    u16* Ash = smem;        u16* Asl = smem + 4096;
    u16* Bsh = smem + 8192; u16* Bsl = smem + 12288;
    const int t = threadIdx.x, w = t >> 6, lane = t & 63;
    const int srow = lane >> 2, skc = (lane & 3) * 8;
    const int ra0 = (w*2+0)*16 + srow, ra1 = (w*2+1)*16 + srow;
    const size_t oA0 = (size_t)ra0 * lda + skc, oA1 = (size_t)ra1 * lda + skc;
    const size_t oB0 = (size_t)ra0 * ldb + skc, oB1 = (size_t)ra1 * ldb + skc;
    const int l0 = (w*2+0)*512, l1 = (w*2+1)*512;
    const int fr = lane & 15, fq = lane >> 4;
    const int wm = (w >> 1) * 64, wn = (w & 1) * 64;
    const int fao = (wm + fr) * 32 + fq * 8;
    const int fbo = (wn + fr) * 32 + fq * 8;

    for (int k0 = 0; k0 < K; k0 += 32) {
        async_copy16(Ah + oA0 + k0, Ash + l0);
        async_copy16(Ah + oA1 + k0, Ash + l1);
        async_copy16(Al + oA0 + k0, Asl + l0);
        async_copy16(Al + oA1 + k0, Asl + l1);
        async_copy16(Bh + oB0 + k0, Bsh + l0);
        async_copy16(Bh + oB1 + k0, Bsh + l1);
        async_copy16(Bl + oB0 + k0, Bsl + l0);
        async_copy16(Bl + oB1 + k0, Bsl + l1);
        __syncthreads();
        bf16x8 afh[4], afl[4], bfh[4], bfl[4];
#pragma unroll
        for (int i = 0; i < 4; i++) {
            afh[i] = *(const bf16x8*)(Ash + fao + i * 512);
            afl[i] = *(const bf16x8*)(Asl + fao + i * 512);
            bfh[i] = *(const bf16x8*)(Bsh + fbo + i * 512);
            bfl[i] = *(const bf16x8*)(Bsl + fbo + i * 512);
        }
#pragma unroll
        for (int mi = 0; mi < 4; mi++)
#pragma unroll
            for (int ni = 0; ni < 4; ni++) {
                acc[mi][ni] = __builtin_amdgcn_mfma_f32_16x16x32_bf16(
                    afh[mi], bfh[ni], acc[mi][ni], 0, 0, 0);
                acc[mi][ni] = __builtin_amdgcn_mfma_f32_16x16x32_bf16(
                    afh[mi], bfl[ni], acc[mi][ni], 0, 0, 0);
                acc[mi][ni] = __builtin_amdgcn_mfma_f32_16x16x32_bf16(
                    afl[mi], bfh[ni], acc[mi][ni], 0, 0, 0);
            }
        __syncthreads();
    }
}

__device__ __forceinline__ void zero_acc(f32x4 acc[4][4]) {
#pragma unroll
    for (int i = 0; i < 4; i++)
#pragma unroll
        for (int j = 0; j < 4; j++) {
            f32x4 z = {0.f, 0.f, 0.f, 0.f};
            acc[i][j] = z;
        }
}

// ---------------------------------------------------------------------------
// Kernel W: split-convert wq/wk/wv f32 -> bf16 hi/lo, packed [3][512][512]
// ---------------------------------------------------------------------------
__global__ __launch_bounds__(256) void k_convw(const float* __restrict__ wq,
                                               const float* __restrict__ wk,
                                               const float* __restrict__ wv,
                                               u16* __restrict__ Whi,
                                               u16* __restrict__ Wlo)
{
    const int t = blockIdx.x * 256 + threadIdx.x;   // 0..196607
    const int e = t * 4;
    const int sel = e >> 18;
    const int off = e & 262143;
    const float* src = (sel == 0) ? wq : (sel == 1) ? wk : wv;
    float4 v = *(const float4*)(src + off);
    ushort4 h, l;
    h.x = f2bf(v.x); l.x = f2bf(v.x - bf2f(h.x));
    h.y = f2bf(v.y); l.y = f2bf(v.y - bf2f(h.y));
    h.z = f2bf(v.z); l.z = f2bf(v.z - bf2f(h.z));
    h.w = f2bf(v.w); l.w = f2bf(v.w - bf2f(h.w));
    *(ushort4*)(Whi + sel * 262144 + off) = h;
    *(ushort4*)(Wlo + sel * 262144 + off) = l;
}

// ---------------------------------------------------------------------------
// Kernel 0: transpose+split X f32 [B,512,4096] -> XThi/XTlo bf16 [B,4096,512]
// ---------------------------------------------------------------------------
__global__ __launch_bounds__(256) void k_transpose(const float* __restrict__ x,
                                                   u16* __restrict__ XThi,
                                                   u16* __restrict__ XTlo)
{
    __shared__ u16 th[64][68];
    __shared__ u16 tl[64][68];
    const int t  = threadIdx.x;
    const int b  = blockIdx.z;
    const int c0 = blockIdx.y * 64;
    const int n0 = blockIdx.x * 64;
    const int rr   = t >> 4;
    const int col4 = (t & 15) * 4;

    const float* src = x + ((size_t)b * 512 + c0) * 4096 + n0;
#pragma unroll
    for (int i = 0; i < 4; i++) {
        int row = i * 16 + rr;
        float4 v = *(const float4*)(src + (size_t)row * 4096 + col4);
        ushort4 h, l;
        h.x = f2bf(v.x); l.x = f2bf(v.x - bf2f(h.x));
        h.y = f2bf(v.y); l.y = f2bf(v.y - bf2f(h.y));
        h.z = f2bf(v.z); l.z = f2bf(v.z - bf2f(h.z));
        h.w = f2bf(v.w); l.w = f2bf(v.w - bf2f(h.w));
        *(ushort4*)&th[row][col4] = h;
        *(ushort4*)&tl[row][col4] = l;
    }
    __syncthreads();
    u16* dh = XThi + ((size_t)b * 4096 + n0) * 512 + c0;
    u16* dl = XTlo + ((size_t)b * 4096 + n0) * 512 + c0;
#pragma unroll
    for (int i = 0; i < 4; i++) {
        int nrow = i * 16 + rr;
        ushort4 oh, ol;
        oh.x = th[col4 + 0][nrow]; ol.x = tl[col4 + 0][nrow];
        oh.y = th[col4 + 1][nrow]; ol.y = tl[col4 + 1][nrow];
        oh.z = th[col4 + 2][nrow]; ol.z = tl[col4 + 2][nrow];
        oh.w = th[col4 + 3][nrow]; ol.w = tl[col4 + 3][nrow];
        *(ushort4*)(dh + (size_t)nrow * 512 + col4) = oh;
        *(ushort4*)(dl + (size_t)nrow * 512 + col4) = ol;
    }
}

// ---------------------------------------------------------------------------
// Kernel 1: Q/K (split-bf16, fp16 out, [C,N]) and V (bf16, [N,C]).
// grid (32 ntiles, 12 mtiles, 8 batches); mtile 0-3 Q, 4-7 K, 8-11 V.
// ---------------------------------------------------------------------------
__global__ __launch_bounds__(256) void k_qkv(
    const u16* __restrict__ Whi, const u16* __restrict__ Wlo,
    const float* __restrict__ bq, const float* __restrict__ bk, const float* __restrict__ bv,
    const u16* __restrict__ XThi, const u16* __restrict__ XTlo,
    u16* __restrict__ Qh, u16* __restrict__ Kh, u16* __restrict__ VT)
{
    __shared__ u16 smem[16384];          // 32 KB
    const int n0  = blockIdx.x * 128;
    const int my  = blockIdx.y;
    const int b   = blockIdx.z;
    const int sel = my >> 2;
    const int m0  = (my & 3) * 128;

    const float* bi = (sel == 0) ? bq : (sel == 1) ? bk : bv;
    const size_t woff = (size_t)sel * 262144 + (size_t)m0 * 512;
    const size_t xoff = ((size_t)b * 4096 + n0) * 512;

    f32x4 acc[4][4];
    zero_acc(acc);

    if (sel < 2) {
        gemm_nt_split(smem, Whi + woff, Wlo + woff, 512,
                      XThi + xoff, XTlo + xoff, 512, 512, acc);
    } else {
        gemm_nt_bf16(smem, Whi + woff, 512, XThi + xoff, 512, 512, acc);
    }

    const int t = threadIdx.x, w = t >> 6, lane = t & 63;
    const int wm = (w >> 1) * 64, wn = (w & 1) * 64;
    const int cn = lane & 15, cq = lane >> 4;

    if (sel < 2) {
        u16* out = ((sel == 0) ? Qh : Kh) + (size_t)b * 512 * 4096;
#pragma unroll
        for (int mi = 0; mi < 4; mi++)
#pragma unroll
            for (int ni = 0; ni < 4; ni++)
#pragma unroll
                for (int r = 0; r < 4; r++) {
                    int m = wm + mi * 16 + cq * 4 + r;
                    int n = wn + ni * 16 + cn;
                    float v = acc[mi][ni][r] + bi[m0 + m];
                    out[(size_t)(m0 + m) * 4096 + n0 + n] = f2h(v);
                }
    } else {
        u16* out = VT + (size_t)b * 4096 * 512;
#pragma unroll
        for (int mi = 0; mi < 4; mi++)
#pragma unroll
            for (int ni = 0; ni < 4; ni++) {
                int n  = wn + ni * 16 + cn;
                int mb = wm + mi * 16 + cq * 4;
                ushort4 pk;
                pk.x = f2bf(acc[mi][ni][0] + bi[m0 + mb + 0]);
                pk.y = f2bf(acc[mi][ni][1] + bi[m0 + mb + 1]);
                pk.z = f2bf(acc[mi][ni][2] + bi[m0 + mb + 2]);
                pk.w = f2bf(acc[mi][ni][3] + bi[m0 + mb + 3]);
                *(ushort4*)(out + (size_t)(n0 + n) * 512 + m0 + mb) = pk;
            }
    }
}

// ---------------------------------------------------------------------------
// Kernel 2: S = Q*K^T (fp16 in, fp32 out), split-K=2.  grid (4,4,16)
// S layout: [ks][b][512][512] fp32
// ---------------------------------------------------------------------------
__global__ __launch_bounds__(256) void k_scores(const u16* __restrict__ Qh,
                                                const u16* __restrict__ Kh,
                                                float* __restrict__ S)
{
    __shared__ u16 smem[8192];           // 16 KB
    const int n0 = blockIdx.x * 128;
    const int m0 = blockIdx.y * 128;
    const int bz = blockIdx.z;
    const int b  = bz >> 1, ks = bz & 1;

    const u16* Ap = Qh + (size_t)b * 512 * 4096 + (size_t)m0 * 4096 + ks * 2048;
    const u16* Bp = Kh + (size_t)b * 512 * 4096 + (size_t)n0 * 4096 + ks * 2048;

    f32x4 acc[4][4];
    zero_acc(acc);
    gemm_nt_f16(smem, Ap, 4096, Bp, 4096, 2048, acc);

    const int t = threadIdx.x, w = t >> 6, lane = t & 63;
    const int wm = (w >> 1) * 64, wn = (w & 1) * 64;
    const int cn = lane & 15, cq = lane >> 4;

    float* out = S + ((size_t)(ks * 8 + b) * 512 + m0) * 512 + n0;
#pragma unroll
    for (int mi = 0; mi < 4; mi++)
#pragma unroll
        for (int ni = 0; ni < 4; ni++)
#pragma unroll
            for (int r = 0; r < 4; r++) {
                int m = wm + mi * 16 + cq * 4 + r;
                int n = wn + ni * 16 + cn;
                out[(size_t)m * 512 + n] = acc[mi][ni][r];
            }
}

// ---------------------------------------------------------------------------
// Kernel 3: softmax rows of (S0+S1) -> P bf16 [b][512][512]
// ---------------------------------------------------------------------------
__global__ __launch_bounds__(256) void k_softmax(const float* __restrict__ S,
                                                 u16* __restrict__ P)
{
    const int row = blockIdx.x;              // b*512 + c
    const int t = threadIdx.x, w = t >> 6, lane = t & 63;
    const float* r0 = S + (size_t)row * 512;
    const float* r1 = S + (size_t)8 * 512 * 512 + (size_t)row * 512;

    float v0 = r0[t] + r1[t];
    float v1 = r0[t + 256] + r1[t + 256];

    float m = fmaxf(v0, v1);
    for (int o = 32; o; o >>= 1) m = fmaxf(m, __shfl_xor(m, o));
    __shared__ float redm[4];
    if (lane == 0) redm[w] = m;
    __syncthreads();
    m = fmaxf(fmaxf(redm[0], redm[1]), fmaxf(redm[2], redm[3]));

    float e0 = __expf(v0 - m), e1 = __expf(v1 - m);
    float s = e0 + e1;
    for (int o = 32; o; o >>= 1) s += __shfl_xor(s, o);
    __shared__ float reds[4];
    if (lane == 0) reds[w] = s;
    __syncthreads();
    s = reds[0] + reds[1] + reds[2] + reds[3];

    float inv = 1.0f / s;
    P[(size_t)row * 512 + t]       = f2bf(e0 * inv);
    P[(size_t)row * 512 + t + 256] = f2bf(e1 * inv);
}

// ---------------------------------------------------------------------------
// Kernel 4: out = P*V + X (f32 out).  grid (32, 4, 8)
// ---------------------------------------------------------------------------
__global__ __launch_bounds__(256) void k_out(const u16* __restrict__ P,
                                             const u16* __restrict__ VT,
                                             const float* __restrict__ x,
                                             float* __restrict__ out)
{
    __shared__ u16 smem[8192];           // 16 KB
    const int n0 = blockIdx.x * 128;
    const int m0 = blockIdx.y * 128;
    const int b  = blockIdx.z;

    const u16* Ap = P  + (size_t)b * 512 * 512 + (size_t)m0 * 512;
    const u16* Bp = VT + (size_t)b * 4096 * 512 + (size_t)n0 * 512;

    f32x4 acc[4][4];
    zero_acc(acc);
    gemm_nt_bf16(smem, Ap, 512, Bp, 512, 512, acc);

    const int t = threadIdx.x, w = t >> 6, lane = t & 63;
    const int wm = (w >> 1) * 64, wn = (w & 1) * 64;
    const int cn = lane & 15, cq = lane >> 4;

#pragma unroll
    for (int mi = 0; mi < 4; mi++)
#pragma unroll
        for (int ni = 0; ni < 4; ni++)
#pragma unroll
            for (int r = 0; r < 4; r++) {
                int m = wm + mi * 16 + cq * 4 + r;
                int n = wn + ni * 16 + cn;
                size_t idx = ((size_t)b * 512 + m0 + m) * 4096 + n0 + n;
                out[idx] = acc[mi][ni][r] + x[idx];
            }
}

// ---------------------------------------------------------------------------
// ws layout (bytes), high-water 170,917,888 (~163 MiB):
//   Whi  [3][512][512] bf16   @ 0           (1572864)
//   Wlo  [3][512][512] bf16   @ 1572864     (1572864)
//   XThi [8][4096][512] bf16  @ 3145728     (33554432)  — dead after k_qkv
//   XTlo [8][4096][512] bf16  @ 36700160    (33554432)  — dead after k_qkv
//   Qh   [8][512][4096] f16   @ 70254592    (33554432)
//   Kh   [8][512][4096] f16   @ 103809024   (33554432)
//   VT   [8][4096][512] bf16  @ 137363456   (33554432)
//   S    [2][8][512][512] f32 @ 3145728     (16777216)  — overlaps dead XThi
//   P    [8][512][512] bf16   @ 19922944    (4194304)   — overlaps dead XThi
// ---------------------------------------------------------------------------
extern "C" void kernel_launch(void* const* d_in, const int* in_sizes, int n_in,
                              void* d_out, int out_size, void* d_ws, size_t ws_size,
                              hipStream_t stream)
{
    const float* x  = (const float*)d_in[0];
    const float* wq = (const float*)d_in[1];
    const float* bq = (const float*)d_in[2];
    const float* wk = (const float*)d_in[3];
    const float* bk = (const float*)d_in[4];
    const float* wv = (const float*)d_in[5];
    const float* bv = (const float*)d_in[6];
    float* out = (float*)d_out;

    char* ws = (char*)d_ws;
    u16*  Whi  = (u16*)(ws);
    u16*  Wlo  = (u16*)(ws + 1572864);
    u16*  XThi = (u16*)(ws + 3145728);
    u16*  XTlo = (u16*)(ws + 36700160);
    u16*  Qh   = (u16*)(ws + 70254592);
    u16*  Kh   = (u16*)(ws + 103809024);
    u16*  VT   = (u16*)(ws + 137363456);
    float* S   = (float*)(ws + 3145728);
    u16*  P    = (u16*)(ws + 19922944);

    k_convw<<<dim3(768), dim3(256), 0, stream>>>(wq, wk, wv, Whi, Wlo);
    k_transpose<<<dim3(64, 8, 8), dim3(256), 0, stream>>>(x, XThi, XTlo);
    k_qkv<<<dim3(32, 12, 8), dim3(256), 0, stream>>>(Whi, Wlo, bq, bk, bv,
                                                     XThi, XTlo, Qh, Kh, VT);
    k_scores<<<dim3(4, 4, 16), dim3(256), 0, stream>>>(Qh, Kh, S);
    k_softmax<<<dim3(4096), dim3(256), 0, stream>>>(S, P);
    k_out<<<dim3(32, 4, 8), dim3(256), 0, stream>>>(P, VT, x, out);
}

// Round 4
// 295.223 us; speedup vs baseline: 1.2234x; 1.2234x over previous
//
#include <hip/hip_runtime.h>
#include <cstdint>

typedef unsigned short u16;
typedef unsigned int   u32;
typedef _Float16 f16;

typedef __attribute__((ext_vector_type(8))) _Float16 f16x8;   // 8 fp16 = 4 VGPRs
typedef __attribute__((ext_vector_type(4))) float    f32x4;   // MFMA accumulator

__device__ __forceinline__ u16 f2h(float f) {
    union { f16 h; u16 u; } c; c.h = (f16)f; return c.u;      // v_cvt_f16_f32 RTNE
}
__device__ __forceinline__ float h2f(u16 u) {
    union { u16 u; f16 h; } c; c.u = u; return (float)c.h;
}

// async global->LDS, 16B per lane; LDS dest = wave-uniform base + lane*16
__device__ __forceinline__ void async_copy16(const u16* g, u16* lds) {
    __builtin_amdgcn_global_load_lds(
        (const __attribute__((address_space(1))) void*)g,
        (__attribute__((address_space(3))) void*)lds,
        16, 0, 0);
}

// ---------------------------------------------------------------------------
// fp16 NT GEMM core: C[128,128] += A[128,K] * B[128,K]^T, K contiguous both.
// 256 thr = 4 waves (2x2), each wave 64x64 = 4x4 MFMA 16x16x32.  BK=32.
// LDS: As[128][32] + Bs[128][32] u16 = 16 KB.
//
// Bank-conflict-free via XOR swizzle: staging lane for within-chunk row r
// fetches k-chunk kc' = (lane&3) ^ ((r>>1)&3)  (pure permutation within the
// row's 64B -> same global segments).  Fragment read at physical chunk
// fq ^ ((fr>>1)&3): 16 lanes spread over 8 bank-groups = 2-way = free.
// ---------------------------------------------------------------------------
__device__ __forceinline__ void gemm_nt_f16(
    u16* smem, const u16* __restrict__ A, int lda,
    const u16* __restrict__ B, int ldb, int K, f32x4 acc[4][4])
{
    u16* As = smem; u16* Bs = smem + 4096;
    const int t = threadIdx.x, w = t >> 6, lane = t & 63;
    const int srow = lane >> 2;                    // 0..15 within chunk
    const int skc  = (((lane & 3) ^ ((lane >> 3) & 3)) * 8);  // swizzled
    const int ra0 = (w*2+0)*16 + srow, ra1 = (w*2+1)*16 + srow;
    const u16* gA0 = A + (size_t)ra0 * lda + skc;
    const u16* gA1 = A + (size_t)ra1 * lda + skc;
    const u16* gB0 = B + (size_t)ra0 * ldb + skc;
    const u16* gB1 = B + (size_t)ra1 * ldb + skc;
    u16* lA0 = As + (w*2+0)*512; u16* lA1 = As + (w*2+1)*512;
    u16* lB0 = Bs + (w*2+0)*512; u16* lB1 = Bs + (w*2+1)*512;
    const int fr = lane & 15, fq = lane >> 4;
    const int fc = (fq ^ ((fr >> 1) & 3)) * 8;     // swizzled fragment chunk
    const int wm = (w >> 1) * 64, wn = (w & 1) * 64;
    const u16* fA = As + (wm + fr) * 32 + fc;
    const u16* fB = Bs + (wn + fr) * 32 + fc;

    for (int k0 = 0; k0 < K; k0 += 32) {
        async_copy16(gA0 + k0, lA0);
        async_copy16(gA1 + k0, lA1);
        async_copy16(gB0 + k0, lB0);
        async_copy16(gB1 + k0, lB1);
        __syncthreads();
        f16x8 af[4], bf[4];
#pragma unroll
        for (int i = 0; i < 4; i++) af[i] = *(const f16x8*)(fA + i * 512);
#pragma unroll
        for (int i = 0; i < 4; i++) bf[i] = *(const f16x8*)(fB + i * 512);
#pragma unroll
        for (int mi = 0; mi < 4; mi++)
#pragma unroll
            for (int ni = 0; ni < 4; ni++)
                acc[mi][ni] = __builtin_amdgcn_mfma_f32_16x16x32_f16(
                    af[mi], bf[ni], acc[mi][ni], 0, 0, 0);
        __syncthreads();
    }
}

__device__ __forceinline__ void zero_acc(f32x4 acc[4][4]) {
#pragma unroll
    for (int i = 0; i < 4; i++)
#pragma unroll
        for (int j = 0; j < 4; j++) {
            f32x4 z = {0.f, 0.f, 0.f, 0.f};
            acc[i][j] = z;
        }
}

// ---------------------------------------------------------------------------
// Kernel W: convert wq/wk/wv f32 -> f16, packed [3][512][512]
// ---------------------------------------------------------------------------
__global__ __launch_bounds__(256) void k_convw(const float* __restrict__ wq,
                                               const float* __restrict__ wk,
                                               const float* __restrict__ wv,
                                               u16* __restrict__ Wf)
{
    const int t = blockIdx.x * 256 + threadIdx.x;   // 0..196607
    const int e = t * 4;
    const int sel = e >> 18;
    const int off = e & 262143;
    const float* src = (sel == 0) ? wq : (sel == 1) ? wk : wv;
    float4 v = *(const float4*)(src + off);
    ushort4 h;
    h.x = f2h(v.x); h.y = f2h(v.y); h.z = f2h(v.z); h.w = f2h(v.w);
    *(ushort4*)(Wf + sel * 262144 + off) = h;
}

// ---------------------------------------------------------------------------
// Kernel 0: transpose+convert X f32 [B,512,4096] -> XT f16 [B,4096,512]
// ---------------------------------------------------------------------------
__global__ __launch_bounds__(256) void k_transpose(const float* __restrict__ x,
                                                   u16* __restrict__ XT)
{
    __shared__ u16 tile[64][70];         // ld=70: write 2-way max, read 2-way
    const int t  = threadIdx.x;
    const int b  = blockIdx.z;
    const int c0 = blockIdx.y * 64;
    const int n0 = blockIdx.x * 64;
    const int rr   = t >> 4;
    const int col4 = (t & 15) * 4;

    const float* src = x + ((size_t)b * 512 + c0) * 4096 + n0;
#pragma unroll
    for (int i = 0; i < 4; i++) {
        int row = i * 16 + rr;
        float4 v = *(const float4*)(src + (size_t)row * 4096 + col4);
        ushort4 h;
        h.x = f2h(v.x); h.y = f2h(v.y); h.z = f2h(v.z); h.w = f2h(v.w);
        *(ushort4*)&tile[row][col4] = h;
    }
    __syncthreads();
    u16* dst = XT + ((size_t)b * 4096 + n0) * 512 + c0;
#pragma unroll
    for (int i = 0; i < 4; i++) {
        int nrow = i * 16 + rr;
        ushort4 o;
        o.x = tile[col4 + 0][nrow];
        o.y = tile[col4 + 1][nrow];
        o.z = tile[col4 + 2][nrow];
        o.w = tile[col4 + 3][nrow];
        *(ushort4*)(dst + (size_t)nrow * 512 + col4) = o;
    }
}

// ---------------------------------------------------------------------------
// Kernel 1: Q/K/V = W*X + bias, all fp16 MFMA.
// grid (32 ntiles, 12 mtiles, 8 batches); mtile 0-3 Q, 4-7 K, 8-11 V.
// Q,K stored f16 [C,N]; V stored f16 [N,C] (transposed epilogue).
// ---------------------------------------------------------------------------
__global__ __launch_bounds__(256) void k_qkv(
    const u16* __restrict__ Wf,
    const float* __restrict__ bq, const float* __restrict__ bk, const float* __restrict__ bv,
    const u16* __restrict__ XT,
    u16* __restrict__ Qh, u16* __restrict__ Kh, u16* __restrict__ VT)
{
    __shared__ u16 smem[8192];           // 16 KB
    const int n0  = blockIdx.x * 128;
    const int my  = blockIdx.y;
    const int b   = blockIdx.z;
    const int sel = my >> 2;
    const int m0  = (my & 3) * 128;

    const float* bi = (sel == 0) ? bq : (sel == 1) ? bk : bv;
    const u16* Ap = Wf + (size_t)sel * 262144 + (size_t)m0 * 512;
    const u16* Bp = XT + ((size_t)b * 4096 + n0) * 512;

    f32x4 acc[4][4];
    zero_acc(acc);
    gemm_nt_f16(smem, Ap, 512, Bp, 512, 512, acc);

    const int t = threadIdx.x, w = t >> 6, lane = t & 63;
    const int wm = (w >> 1) * 64, wn = (w & 1) * 64;
    const int cn = lane & 15, cq = lane >> 4;

    if (sel < 2) {
        u16* out = ((sel == 0) ? Qh : Kh) + (size_t)b * 512 * 4096;
#pragma unroll
        for (int mi = 0; mi < 4; mi++)
#pragma unroll
            for (int ni = 0; ni < 4; ni++)
#pragma unroll
                for (int r = 0; r < 4; r++) {
                    int m = wm + mi * 16 + cq * 4 + r;
                    int n = wn + ni * 16 + cn;
                    out[(size_t)(m0 + m) * 4096 + n0 + n] =
                        f2h(acc[mi][ni][r] + bi[m0 + m]);
                }
    } else {
        u16* out = VT + (size_t)b * 4096 * 512;
#pragma unroll
        for (int mi = 0; mi < 4; mi++)
#pragma unroll
            for (int ni = 0; ni < 4; ni++) {
                int n  = wn + ni * 16 + cn;
                int mb = wm + mi * 16 + cq * 4;
                ushort4 pk;
                pk.x = f2h(acc[mi][ni][0] + bi[m0 + mb + 0]);
                pk.y = f2h(acc[mi][ni][1] + bi[m0 + mb + 1]);
                pk.z = f2h(acc[mi][ni][2] + bi[m0 + mb + 2]);
                pk.w = f2h(acc[mi][ni][3] + bi[m0 + mb + 3]);
                *(ushort4*)(out + (size_t)(n0 + n) * 512 + m0 + mb) = pk;
            }
    }
}

// ---------------------------------------------------------------------------
// Kernel 2: S = Q*K^T (fp16 in, fp32 out), split-K=4.  grid (4,4,32)
// S layout: [ks][b][512][512] fp32
// ---------------------------------------------------------------------------
__global__ __launch_bounds__(256) void k_scores(const u16* __restrict__ Qh,
                                                const u16* __restrict__ Kh,
                                                float* __restrict__ S)
{
    __shared__ u16 smem[8192];
    const int n0 = blockIdx.x * 128;
    const int m0 = blockIdx.y * 128;
    const int bz = blockIdx.z;
    const int b  = bz >> 2, ks = bz & 3;

    const u16* Ap = Qh + (size_t)b * 512 * 4096 + (size_t)m0 * 4096 + ks * 1024;
    const u16* Bp = Kh + (size_t)b * 512 * 4096 + (size_t)n0 * 4096 + ks * 1024;

    f32x4 acc[4][4];
    zero_acc(acc);
    gemm_nt_f16(smem, Ap, 4096, Bp, 4096, 1024, acc);

    const int t = threadIdx.x, w = t >> 6, lane = t & 63;
    const int wm = (w >> 1) * 64, wn = (w & 1) * 64;
    const int cn = lane & 15, cq = lane >> 4;

    float* out = S + ((size_t)(ks * 8 + b) * 512 + m0) * 512 + n0;
#pragma unroll
    for (int mi = 0; mi < 4; mi++)
#pragma unroll
        for (int ni = 0; ni < 4; ni++)
#pragma unroll
            for (int r = 0; r < 4; r++) {
                int m = wm + mi * 16 + cq * 4 + r;
                int n = wn + ni * 16 + cn;
                out[(size_t)m * 512 + n] = acc[mi][ni][r];
            }
}

// ---------------------------------------------------------------------------
// Kernel 3: softmax rows of (S0+S1+S2+S3) -> P f16 [b][512][512]
// ---------------------------------------------------------------------------
__global__ __launch_bounds__(256) void k_softmax(const float* __restrict__ S,
                                                 u16* __restrict__ P)
{
    const int row = blockIdx.x;              // b*512 + c
    const int t = threadIdx.x, w = t >> 6, lane = t & 63;
    const size_t st = (size_t)8 * 512 * 512;
    const float* r0 = S + (size_t)row * 512;

    float v0 = r0[t]       + r0[t + st]       + r0[t + 2*st]       + r0[t + 3*st];
    float v1 = r0[t + 256] + r0[t + 256 + st] + r0[t + 256 + 2*st] + r0[t + 256 + 3*st];

    float m = fmaxf(v0, v1);
    for (int o = 32; o; o >>= 1) m = fmaxf(m, __shfl_xor(m, o));
    __shared__ float redm[4];
    if (lane == 0) redm[w] = m;
    __syncthreads();
    m = fmaxf(fmaxf(redm[0], redm[1]), fmaxf(redm[2], redm[3]));

    float e0 = __expf(v0 - m), e1 = __expf(v1 - m);
    float s = e0 + e1;
    for (int o = 32; o; o >>= 1) s += __shfl_xor(s, o);
    __shared__ float reds[4];
    if (lane == 0) reds[w] = s;
    __syncthreads();
    s = reds[0] + reds[1] + reds[2] + reds[3];

    float inv = 1.0f / s;
    P[(size_t)row * 512 + t]       = f2h(e0 * inv);
    P[(size_t)row * 512 + t + 256] = f2h(e1 * inv);
}

// ---------------------------------------------------------------------------
// Kernel 4: out = P*V + X (f32 out).  grid (32, 4, 8)
// ---------------------------------------------------------------------------
__global__ __launch_bounds__(256) void k_out(const u16* __restrict__ P,
                                             const u16* __restrict__ VT,
                                             const float* __restrict__ x,
                                             float* __restrict__ out)
{
    __shared__ u16 smem[8192];
    const int n0 = blockIdx.x * 128;
    const int m0 = blockIdx.y * 128;
    const int b  = blockIdx.z;

    const u16* Ap = P  + (size_t)b * 512 * 512 + (size_t)m0 * 512;
    const u16* Bp = VT + (size_t)b * 4096 * 512 + (size_t)n0 * 512;

    f32x4 acc[4][4];
    zero_acc(acc);
    gemm_nt_f16(smem, Ap, 512, Bp, 512, 512, acc);

    const int t = threadIdx.x, w = t >> 6, lane = t & 63;
    const int wm = (w >> 1) * 64, wn = (w & 1) * 64;
    const int cn = lane & 15, cq = lane >> 4;

#pragma unroll
    for (int mi = 0; mi < 4; mi++)
#pragma unroll
        for (int ni = 0; ni < 4; ni++)
#pragma unroll
            for (int r = 0; r < 4; r++) {
                int m = wm + mi * 16 + cq * 4 + r;
                int n = wn + ni * 16 + cn;
                size_t idx = ((size_t)b * 512 + m0 + m) * 4096 + n0 + n;
                out[idx] = acc[mi][ni][r] + x[idx];
            }
}

// ---------------------------------------------------------------------------
// ws layout (bytes), high-water ~133.5 MiB:
//   Wf  [3][512][512] f16    @ 0           (1572864)
//   XT  [8][4096][512] f16   @ 1572864     (33554432) — dead after k_qkv
//   Qh  [8][512][4096] f16   @ 35127296    (33554432)
//   Kh  [8][512][4096] f16   @ 68681728    (33554432)
//   VT  [8][4096][512] f16   @ 102236160   (33554432)
//   S   [4][8][512][512] f32 @ 1572864     (33554432) — overlaps dead XT
//   P   [8][512][512] f16    @ 135790592   (4194304)
// ---------------------------------------------------------------------------
extern "C" void kernel_launch(void* const* d_in, const int* in_sizes, int n_in,
                              void* d_out, int out_size, void* d_ws, size_t ws_size,
                              hipStream_t stream)
{
    const float* x  = (const float*)d_in[0];
    const float* wq = (const float*)d_in[1];
    const float* bq = (const float*)d_in[2];
    const float* wk = (const float*)d_in[3];
    const float* bk = (const float*)d_in[4];
    const float* wv = (const float*)d_in[5];
    const float* bv = (const float*)d_in[6];
    float* out = (float*)d_out;

    char* ws = (char*)d_ws;
    u16*  Wf = (u16*)(ws);
    u16*  XT = (u16*)(ws + 1572864);
    u16*  Qh = (u16*)(ws + 35127296);
    u16*  Kh = (u16*)(ws + 68681728);
    u16*  VT = (u16*)(ws + 102236160);
    float* S = (float*)(ws + 1572864);      // overlaps dead XT
    u16*  P  = (u16*)(ws + 135790592);

    k_convw<<<dim3(768), dim3(256), 0, stream>>>(wq, wk, wv, Wf);
    k_transpose<<<dim3(64, 8, 8), dim3(256), 0, stream>>>(x, XT);
    k_qkv<<<dim3(32, 12, 8), dim3(256), 0, stream>>>(Wf, bq, bk, bv, XT, Qh, Kh, VT);
    k_scores<<<dim3(4, 4, 32), dim3(256), 0, stream>>>(Qh, Kh, S);
    k_softmax<<<dim3(4096), dim3(256), 0, stream>>>(S, P);
    k_out<<<dim3(32, 4, 8), dim3(256), 0, stream>>>(P, VT, x, out);
}